// Round 2
// baseline (5471.412 us; speedup 1.0000x reference)
//
#include <hip/hip_runtime.h>

#define BN_EPS 1e-5f

// ---------------------------------------------------------------- degree ----
__global__ __launch_bounds__(256) void k_init_deg(float* deg, int N) {
    int i = blockIdx.x * 256 + threadIdx.x;
    if (i < N) deg[i] = 1.0f;  // self-loop
}

__global__ __launch_bounds__(256) void k_count_deg(const int* __restrict__ ei,
                                                   float* __restrict__ deg, int E, int N) {
    int e = blockIdx.x * 256 + threadIdx.x;
    if (e < E) {
        int d = ei[E + e];
        if ((unsigned)d < (unsigned)N) unsafeAtomicAdd(&deg[d], 1.0f);
    }
}

__global__ __launch_bounds__(256) void k_dinv(float* deg, int N) {
    int i = blockIdx.x * 256 + threadIdx.x;
    if (i < N) deg[i] = rsqrtf(deg[i]);   // deg >= 1 always
}

// ---------------------------------------------------------------- W2 pad ----
__global__ __launch_bounds__(256) void k_padW2(const float* __restrict__ W2,
                                               float* __restrict__ wp) {
    int t = blockIdx.x * 256 + threadIdx.x;   // 16384 total
    int k = t >> 7, c = t & 127;
    wp[t] = (c < 40) ? W2[k * 40 + c] : 0.0f;
}

// ------------------------------------------------------------------ GEMM ----
// H[N,128] = bn_relu(X)[N,128] @ W[128,128].  BN fused into the LDS tile load
// (stats==nullptr -> identity).  32 rows/block, 4x4 micro-tile per thread.
__device__ __forceinline__ float bn_apply(float v, int c, const float* stats,
                                          const float* g, const float* be, float invN) {
    float mean = stats[c] * invN;
    float var  = fmaf(-mean, mean, stats[128 + c] * invN);
    float sc   = g[c] * rsqrtf(var + BN_EPS);
    float r    = fmaf(v - mean, sc, be[c]);
    return fmaxf(r, 0.0f);
}

__global__ __launch_bounds__(256) void k_gemm128(
        const float* __restrict__ X, const float* __restrict__ W,
        float* __restrict__ H, int N,
        const float* __restrict__ stats, const float* __restrict__ g,
        const float* __restrict__ be) {
    __shared__ float xs[32][128];
    const int tid = threadIdx.x;
    const int rowbase = blockIdx.x * 32;
    const float invN = 1.0f / (float)N;

    // stage 32x128 X tile (BN+ReLU fused)
    for (int i = tid; i < 1024; i += 256) {
        int r = i >> 5, c4 = i & 31;
        int gr = rowbase + r;
        float t0 = 0.f, t1 = 0.f, t2 = 0.f, t3 = 0.f;
        if (gr < N) {
            float4 v = ((const float4*)(X + (size_t)gr * 128))[c4];
            t0 = v.x; t1 = v.y; t2 = v.z; t3 = v.w;
            if (stats) {
                int c = c4 * 4;
                t0 = bn_apply(t0, c + 0, stats, g, be, invN);
                t1 = bn_apply(t1, c + 1, stats, g, be, invN);
                t2 = bn_apply(t2, c + 2, stats, g, be, invN);
                t3 = bn_apply(t3, c + 3, stats, g, be, invN);
            }
        }
        *((float4*)&xs[r][c4 * 4]) = make_float4(t0, t1, t2, t3);
    }
    __syncthreads();

    const int cg = tid & 31;     // col group (4 cols)
    const int rg = tid >> 5;     // row group (4 rows) — wave-uniform pairs -> LDS broadcast
    float acc[4][4];
    #pragma unroll
    for (int r = 0; r < 4; ++r)
        #pragma unroll
        for (int c = 0; c < 4; ++c) acc[r][c] = 0.0f;

    const float4* Wv = (const float4*)W;
    const float* x0p = xs[rg * 4 + 0];
    const float* x1p = xs[rg * 4 + 1];
    const float* x2p = xs[rg * 4 + 2];
    const float* x3p = xs[rg * 4 + 3];

    #pragma unroll 8
    for (int k = 0; k < 128; ++k) {
        float4 w = Wv[(k << 5) + cg];
        float a0 = x0p[k], a1 = x1p[k], a2 = x2p[k], a3 = x3p[k];
        acc[0][0] = fmaf(a0, w.x, acc[0][0]); acc[0][1] = fmaf(a0, w.y, acc[0][1]);
        acc[0][2] = fmaf(a0, w.z, acc[0][2]); acc[0][3] = fmaf(a0, w.w, acc[0][3]);
        acc[1][0] = fmaf(a1, w.x, acc[1][0]); acc[1][1] = fmaf(a1, w.y, acc[1][1]);
        acc[1][2] = fmaf(a1, w.z, acc[1][2]); acc[1][3] = fmaf(a1, w.w, acc[1][3]);
        acc[2][0] = fmaf(a2, w.x, acc[2][0]); acc[2][1] = fmaf(a2, w.y, acc[2][1]);
        acc[2][2] = fmaf(a2, w.z, acc[2][2]); acc[2][3] = fmaf(a2, w.w, acc[2][3]);
        acc[3][0] = fmaf(a3, w.x, acc[3][0]); acc[3][1] = fmaf(a3, w.y, acc[3][1]);
        acc[3][2] = fmaf(a3, w.z, acc[3][2]); acc[3][3] = fmaf(a3, w.w, acc[3][3]);
    }

    #pragma unroll
    for (int r = 0; r < 4; ++r) {
        int row = rowbase + rg * 4 + r;
        if (row < N)
            ((float4*)(H + (size_t)row * 128))[cg] =
                make_float4(acc[r][0], acc[r][1], acc[r][2], acc[r][3]);
    }
}

// --------------------------------------------------------------- scatter ----
// out[i] = H[i]*dinv[i]^2 + b   (writes EVERY element -> also the zero-init)
__global__ __launch_bounds__(256) void k_selfloop128(
        const float* __restrict__ H, const float* __restrict__ dinv,
        const float* __restrict__ b, float* __restrict__ out, int N) {
    int t = blockIdx.x * 256 + threadIdx.x;     // N*32 float4 tasks
    int row = t >> 5, cg = t & 31;
    if (row >= N) return;
    float di = dinv[row];
    float nn = di * di;
    float4 v = ((const float4*)(H + (size_t)row * 128))[cg];
    float4 bb = ((const float4*)b)[cg];
    ((float4*)(out + (size_t)row * 128))[cg] =
        make_float4(fmaf(v.x, nn, bb.x), fmaf(v.y, nn, bb.y),
                    fmaf(v.z, nn, bb.z), fmaf(v.w, nn, bb.w));
}

// out[dst] += H[src]*norm : 32 lanes per edge, 4 fp32 atomics/lane
__global__ __launch_bounds__(256) void k_edge128(
        const float* __restrict__ H, const int* __restrict__ ei,
        const float* __restrict__ dinv, float* __restrict__ out, int E, int N) {
    int e = blockIdx.x * 8 + (threadIdx.x >> 5);
    if (e >= E) return;
    int lane = threadIdx.x & 31;
    int s = ei[e];
    int d = ei[E + e];
    if ((unsigned)s >= (unsigned)N || (unsigned)d >= (unsigned)N) return;
    float nrm = dinv[s] * dinv[d];
    float4 v = ((const float4*)(H + (size_t)s * 128))[lane];
    float* o = out + (size_t)d * 128 + lane * 4;
    unsafeAtomicAdd(o + 0, v.x * nrm);
    unsafeAtomicAdd(o + 1, v.y * nrm);
    unsafeAtomicAdd(o + 2, v.z * nrm);
    unsafeAtomicAdd(o + 3, v.w * nrm);
}

// 40-channel variants (reads H with stride 128 — only cols 0..39 valid)
__global__ __launch_bounds__(256) void k_selfloop40(
        const float* __restrict__ H, const float* __restrict__ dinv,
        const float* __restrict__ b, float* __restrict__ out, int N) {
    int t = blockIdx.x * 256 + threadIdx.x;     // N*10 float4 tasks
    int row = t / 10, cg = t % 10;
    if (row >= N) return;
    float di = dinv[row];
    float nn = di * di;
    float4 v = ((const float4*)(H + (size_t)row * 128))[cg];
    float4 bb = ((const float4*)b)[cg];
    ((float4*)(out + (size_t)row * 40))[cg] =
        make_float4(fmaf(v.x, nn, bb.x), fmaf(v.y, nn, bb.y),
                    fmaf(v.z, nn, bb.z), fmaf(v.w, nn, bb.w));
}

__global__ __launch_bounds__(256) void k_edge40(
        const float* __restrict__ H, const int* __restrict__ ei,
        const float* __restrict__ dinv, float* __restrict__ out, int E, int N) {
    int t = blockIdx.x * 256 + threadIdx.x;     // E*10 tasks
    int e = t / 10, cg = t % 10;
    if (e >= E) return;
    int s = ei[e];
    int d = ei[E + e];
    if ((unsigned)s >= (unsigned)N || (unsigned)d >= (unsigned)N) return;
    float nrm = dinv[s] * dinv[d];
    float4 v = ((const float4*)(H + (size_t)s * 128))[cg];
    float* o = out + (size_t)d * 40 + cg * 4;
    unsafeAtomicAdd(o + 0, v.x * nrm);
    unsafeAtomicAdd(o + 1, v.y * nrm);
    unsafeAtomicAdd(o + 2, v.z * nrm);
    unsafeAtomicAdd(o + 3, v.w * nrm);
}

// -------------------------------------------------------------- BN stats ----
__global__ __launch_bounds__(128) void k_bnstats(
        const float* __restrict__ H, float* __restrict__ stats, int N) {
    int c = threadIdx.x;  // 128 threads = one channel each
    float s = 0.f, s2 = 0.f;
    for (int r = blockIdx.x; r < N; r += gridDim.x) {
        float v = H[(size_t)r * 128 + c];
        s += v;
        s2 = fmaf(v, v, s2);
    }
    unsafeAtomicAdd(&stats[c], s);
    unsafeAtomicAdd(&stats[128 + c], s2);
}

// ---------------------------------------------------------------- launch ----
extern "C" void kernel_launch(void* const* d_in, const int* in_sizes, int n_in,
                              void* d_out, int out_size, void* d_ws, size_t ws_size,
                              hipStream_t stream) {
    const float* x   = (const float*)d_in[0];
    const int*   ei  = (const int*)d_in[1];      // int64 in ref -> int32 from harness
    const float* W0  = (const float*)d_in[2];
    const float* b0  = (const float*)d_in[3];
    const float* g0  = (const float*)d_in[4];
    const float* be0 = (const float*)d_in[5];
    const float* W1  = (const float*)d_in[6];
    const float* b1  = (const float*)d_in[7];
    const float* g1  = (const float*)d_in[8];
    const float* be1 = (const float*)d_in[9];
    const float* W2  = (const float*)d_in[10];
    const float* b2  = (const float*)d_in[11];
    float* out = (float*)d_out;

    const int N = in_sizes[0] / 128;   // 170000
    const int E = in_sizes[1] / 2;     // 1200000

    // workspace layout (floats): dinv | stats0 | stats1 | w2pad | bufA | bufB
    float* ws     = (float*)d_ws;
    size_t Npad   = ((size_t)N + 511) & ~(size_t)511;
    float* dinv   = ws;
    float* stats0 = ws + Npad;
    float* stats1 = stats0 + 256;
    float* w2pad  = stats1 + 256;
    float* bufA   = w2pad + 16384;
    float* bufB   = bufA + (size_t)N * 128;

    hipMemsetAsync(stats0, 0, 512 * sizeof(float), stream);  // stats0+stats1

    k_init_deg <<<(N + 255) / 256, 256, 0, stream>>>(dinv, N);
    k_count_deg<<<(E + 255) / 256, 256, 0, stream>>>(ei, dinv, E, N);
    k_dinv     <<<(N + 255) / 256, 256, 0, stream>>>(dinv, N);
    k_padW2    <<<64, 256, 0, stream>>>(W2, w2pad);

    int gemm_grid  = (N + 31) / 32;
    int sl128_grid = (N * 32 + 255) / 256;
    int e128_grid  = (E + 7) / 8;
    int sl40_grid  = (N * 10 + 255) / 256;
    int e40_grid   = ((E * 10) + 255) / 256;

    // ---- layer 0: conv(x, W0) + b0 ----
    k_gemm128    <<<gemm_grid, 256, 0, stream>>>(x, W0, bufA, N, nullptr, nullptr, nullptr);
    k_selfloop128<<<sl128_grid, 256, 0, stream>>>(bufA, dinv, b0, bufB, N);
    k_edge128    <<<e128_grid, 256, 0, stream>>>(bufA, ei, dinv, bufB, E, N);
    k_bnstats    <<<1024, 128, 0, stream>>>(bufB, stats0, N);

    // ---- layer 1: conv(bn_relu(h), W1) + b1  (BN fused into GEMM load) ----
    k_gemm128    <<<gemm_grid, 256, 0, stream>>>(bufB, W1, bufA, N, stats0, g0, be0);
    k_selfloop128<<<sl128_grid, 256, 0, stream>>>(bufA, dinv, b1, bufB, N);
    k_edge128    <<<e128_grid, 256, 0, stream>>>(bufA, ei, dinv, bufB, E, N);
    k_bnstats    <<<1024, 128, 0, stream>>>(bufB, stats1, N);

    // ---- layer 2: conv(bn_relu(h), W2pad) + b2 -> d_out (40 ch) ----
    k_gemm128    <<<gemm_grid, 256, 0, stream>>>(bufB, w2pad, bufA, N, stats1, g1, be1);
    k_selfloop40 <<<sl40_grid, 256, 0, stream>>>(bufA, dinv, b2, out, N);
    k_edge40     <<<e40_grid, 256, 0, stream>>>(bufA, ei, dinv, out, E, N);
}

// Round 3
// 1089.791 us; speedup vs baseline: 5.0206x; 5.0206x over previous
//
#include <hip/hip_runtime.h>

#define BN_EPS 1e-5f

// =========================== CSR build (per call) ===========================
__global__ __launch_bounds__(256) void k_count(const int* __restrict__ ei,
                                               int* __restrict__ cnt, int E, int N) {
    int e = blockIdx.x * 256 + threadIdx.x;
    if (e < E) {
        int d = ei[E + e];
        if ((unsigned)d < (unsigned)N) atomicAdd(&cnt[d], 1);
    }
}

__global__ __launch_bounds__(256) void k_dinv(const int* __restrict__ cnt,
                                              float* __restrict__ dinv, int N) {
    int i = blockIdx.x * 256 + threadIdx.x;
    if (i < N) dinv[i] = rsqrtf((float)(1 + cnt[i]));  // +1 self-loop
}

// 3-kernel exclusive scan over rs[0..N-1] (in place). nb must be <= 1024.
__global__ __launch_bounds__(256) void k_scan_part(int* __restrict__ rs,
                                                   int* __restrict__ bsum, int N) {
    __shared__ int s[256];
    int i = blockIdx.x * 256 + threadIdx.x;
    int v = (i < N) ? rs[i] : 0;
    s[threadIdx.x] = v;
    __syncthreads();
    for (int off = 1; off < 256; off <<= 1) {
        int t = (threadIdx.x >= off) ? s[threadIdx.x - off] : 0;
        __syncthreads();
        s[threadIdx.x] += t;
        __syncthreads();
    }
    if (i < N) rs[i] = s[threadIdx.x] - v;            // exclusive
    if (threadIdx.x == 255) bsum[blockIdx.x] = s[255];
}

__global__ __launch_bounds__(1024) void k_scan_sums(int* __restrict__ bsum, int nb) {
    __shared__ int s[1024];
    int v = (threadIdx.x < nb) ? bsum[threadIdx.x] : 0;
    s[threadIdx.x] = v;
    __syncthreads();
    for (int off = 1; off < 1024; off <<= 1) {
        int t = (threadIdx.x >= off) ? s[threadIdx.x - off] : 0;
        __syncthreads();
        s[threadIdx.x] += t;
        __syncthreads();
    }
    if (threadIdx.x < nb) bsum[threadIdx.x] = s[threadIdx.x] - v;  // exclusive
}

__global__ __launch_bounds__(256) void k_scan_add(int* __restrict__ rs,
                                                  const int* __restrict__ bsum, int N) {
    int i = blockIdx.x * 256 + threadIdx.x;
    if (i < N) rs[i] += bsum[blockIdx.x];
}

// post-increment fill: afterwards rs[d] == end offset of node d (== start[d+1])
__global__ __launch_bounds__(256) void k_fill(const int* __restrict__ ei,
                                              int* __restrict__ rs,
                                              int* __restrict__ csr_src, int E, int N) {
    int e = blockIdx.x * 256 + threadIdx.x;
    if (e >= E) return;
    int s = ei[e], d = ei[E + e];
    if ((unsigned)s >= (unsigned)N || (unsigned)d >= (unsigned)N) return;
    int pos = atomicAdd(&rs[d], 1);
    csr_src[pos] = s;
}

// ================================ W2 pad ====================================
__global__ __launch_bounds__(256) void k_padW2(const float* __restrict__ W2,
                                               float* __restrict__ wp) {
    int t = blockIdx.x * 256 + threadIdx.x;   // 16384
    int k = t >> 7, c = t & 127;
    wp[t] = (c < 40) ? W2[k * 40 + c] : 0.0f;
}

// ================================= GEMM =====================================
__device__ __forceinline__ float bn_apply(float v, int c, const float* stats,
                                          const float* g, const float* be, float invN) {
    float mean = stats[c] * invN;
    float var  = fmaf(-mean, mean, stats[128 + c] * invN);
    float sc   = g[c] * rsqrtf(var + BN_EPS);
    float r    = fmaf(v - mean, sc, be[c]);
    return fmaxf(r, 0.0f);
}

// H[N,128] = bn_relu(X) @ W.  32 rows/block, 4x4 micro-tile, float4 k-tiles.
__global__ __launch_bounds__(256) void k_gemm128(
        const float* __restrict__ X, const float* __restrict__ W,
        float* __restrict__ H, int N,
        const float* __restrict__ stats, const float* __restrict__ g,
        const float* __restrict__ be) {
    __shared__ float xs[32][128];
    const int tid = threadIdx.x;
    const int rowbase = blockIdx.x * 32;
    const float invN = 1.0f / (float)N;

    for (int i = tid; i < 1024; i += 256) {
        int r = i >> 5, c4 = i & 31;
        int gr = rowbase + r;
        float t0 = 0.f, t1 = 0.f, t2 = 0.f, t3 = 0.f;
        if (gr < N) {
            float4 v = ((const float4*)(X + (size_t)gr * 128))[c4];
            t0 = v.x; t1 = v.y; t2 = v.z; t3 = v.w;
            if (stats) {
                int c = c4 * 4;
                t0 = bn_apply(t0, c + 0, stats, g, be, invN);
                t1 = bn_apply(t1, c + 1, stats, g, be, invN);
                t2 = bn_apply(t2, c + 2, stats, g, be, invN);
                t3 = bn_apply(t3, c + 3, stats, g, be, invN);
            }
        }
        *((float4*)&xs[r][c4 * 4]) = make_float4(t0, t1, t2, t3);
    }
    __syncthreads();

    const int cg = tid & 31;     // 4 output cols
    const int rg = tid >> 5;     // 4 rows; lane-invariant per 32-lane group -> LDS broadcast
    float acc[4][4];
    #pragma unroll
    for (int r = 0; r < 4; ++r)
        #pragma unroll
        for (int c = 0; c < 4; ++c) acc[r][c] = 0.0f;

    const float4* Wv  = (const float4*)W;
    const float4* xv0 = (const float4*)xs[rg * 4 + 0];
    const float4* xv1 = (const float4*)xs[rg * 4 + 1];
    const float4* xv2 = (const float4*)xs[rg * 4 + 2];
    const float4* xv3 = (const float4*)xs[rg * 4 + 3];

#define ACCR(r, ar) \
    acc[r][0]=fmaf(ar.x,w0.x,fmaf(ar.y,w1.x,fmaf(ar.z,w2.x,fmaf(ar.w,w3.x,acc[r][0])))); \
    acc[r][1]=fmaf(ar.x,w0.y,fmaf(ar.y,w1.y,fmaf(ar.z,w2.y,fmaf(ar.w,w3.y,acc[r][1])))); \
    acc[r][2]=fmaf(ar.x,w0.z,fmaf(ar.y,w1.z,fmaf(ar.z,w2.z,fmaf(ar.w,w3.z,acc[r][2])))); \
    acc[r][3]=fmaf(ar.x,w0.w,fmaf(ar.y,w1.w,fmaf(ar.z,w2.w,fmaf(ar.w,w3.w,acc[r][3]))));

    #pragma unroll 4
    for (int k4 = 0; k4 < 32; ++k4) {
        float4 a0 = xv0[k4], a1 = xv1[k4], a2 = xv2[k4], a3 = xv3[k4];
        float4 w0 = Wv[(k4 * 4 + 0) * 32 + cg];
        float4 w1 = Wv[(k4 * 4 + 1) * 32 + cg];
        float4 w2 = Wv[(k4 * 4 + 2) * 32 + cg];
        float4 w3 = Wv[(k4 * 4 + 3) * 32 + cg];
        ACCR(0, a0) ACCR(1, a1) ACCR(2, a2) ACCR(3, a3)
    }
#undef ACCR

    #pragma unroll
    for (int r = 0; r < 4; ++r) {
        int row = rowbase + rg * 4 + r;
        if (row < N)
            ((float4*)(H + (size_t)row * 128))[cg] =
                make_float4(acc[r][0], acc[r][1], acc[r][2], acc[r][3]);
    }
}

// ========================= gather-based aggregate ===========================
// out[d] = b + H[d]*dinv[d]^2 + sum_{s in nbr(d)} H[s]*dinv[s]*dinv[d]
// rs_end[d] = end offset of node d (begin = rs_end[d-1], 0 for d==0)
__global__ __launch_bounds__(256) void k_agg128(
        const float* __restrict__ H, const int* __restrict__ rs_end,
        const int* __restrict__ csr_src, const float* __restrict__ dinv,
        const float* __restrict__ b, float* __restrict__ out, int N) {
    int lane = threadIdx.x & 31;
    int node = blockIdx.x * 8 + (threadIdx.x >> 5);
    if (node >= N) return;
    float dd  = dinv[node];
    int   beg = (node == 0) ? 0 : rs_end[node - 1];
    int   end = rs_end[node];
    float4 h  = ((const float4*)(H + (size_t)node * 128))[lane];
    float4 bb = ((const float4*)b)[lane];
    float  sl = dd * dd;
    float4 acc = make_float4(fmaf(h.x, sl, bb.x), fmaf(h.y, sl, bb.y),
                             fmaf(h.z, sl, bb.z), fmaf(h.w, sl, bb.w));
    int j = beg;
    for (; j + 2 <= end; j += 2) {           // unroll 2 for MLP
        int s0 = csr_src[j], s1 = csr_src[j + 1];
        float n0 = dinv[s0] * dd, n1 = dinv[s1] * dd;
        float4 v0 = ((const float4*)(H + (size_t)s0 * 128))[lane];
        float4 v1 = ((const float4*)(H + (size_t)s1 * 128))[lane];
        acc.x = fmaf(v0.x, n0, fmaf(v1.x, n1, acc.x));
        acc.y = fmaf(v0.y, n0, fmaf(v1.y, n1, acc.y));
        acc.z = fmaf(v0.z, n0, fmaf(v1.z, n1, acc.z));
        acc.w = fmaf(v0.w, n0, fmaf(v1.w, n1, acc.w));
    }
    if (j < end) {
        int s0 = csr_src[j];
        float n0 = dinv[s0] * dd;
        float4 v0 = ((const float4*)(H + (size_t)s0 * 128))[lane];
        acc.x = fmaf(v0.x, n0, acc.x); acc.y = fmaf(v0.y, n0, acc.y);
        acc.z = fmaf(v0.z, n0, acc.z); acc.w = fmaf(v0.w, n0, acc.w);
    }
    ((float4*)(out + (size_t)node * 128))[lane] = acc;
}

// 40-ch final: 16-lane groups, lanes 0..9 carry float4 (H stride 128, cols 0..39)
__global__ __launch_bounds__(256) void k_agg40(
        const float* __restrict__ H, const int* __restrict__ rs_end,
        const int* __restrict__ csr_src, const float* __restrict__ dinv,
        const float* __restrict__ b, float* __restrict__ out, int N) {
    int lane = threadIdx.x & 15;
    int node = blockIdx.x * 16 + (threadIdx.x >> 4);
    if (node >= N || lane >= 10) return;
    float dd  = dinv[node];
    int   beg = (node == 0) ? 0 : rs_end[node - 1];
    int   end = rs_end[node];
    float4 h  = ((const float4*)(H + (size_t)node * 128))[lane];
    float4 bb = ((const float4*)b)[lane];
    float  sl = dd * dd;
    float4 acc = make_float4(fmaf(h.x, sl, bb.x), fmaf(h.y, sl, bb.y),
                             fmaf(h.z, sl, bb.z), fmaf(h.w, sl, bb.w));
    for (int j = beg; j < end; ++j) {
        int s0 = csr_src[j];
        float n0 = dinv[s0] * dd;
        float4 v0 = ((const float4*)(H + (size_t)s0 * 128))[lane];
        acc.x = fmaf(v0.x, n0, acc.x); acc.y = fmaf(v0.y, n0, acc.y);
        acc.z = fmaf(v0.z, n0, acc.z); acc.w = fmaf(v0.w, n0, acc.w);
    }
    ((float4*)(out + (size_t)node * 40))[lane] = acc;
}

// =============================== BN stats ===================================
__global__ __launch_bounds__(128) void k_bnstats(
        const float* __restrict__ H, float* __restrict__ stats, int N) {
    int c = threadIdx.x;
    float s = 0.f, s2 = 0.f;
    for (int r = blockIdx.x; r < N; r += gridDim.x) {
        float v = H[(size_t)r * 128 + c];
        s += v;
        s2 = fmaf(v, v, s2);
    }
    unsafeAtomicAdd(&stats[c], s);
    unsafeAtomicAdd(&stats[128 + c], s2);
}

// ================================ launch ====================================
extern "C" void kernel_launch(void* const* d_in, const int* in_sizes, int n_in,
                              void* d_out, int out_size, void* d_ws, size_t ws_size,
                              hipStream_t stream) {
    const float* x   = (const float*)d_in[0];
    const int*   ei  = (const int*)d_in[1];      // int64 in ref -> int32 from harness
    const float* W0  = (const float*)d_in[2];
    const float* b0  = (const float*)d_in[3];
    const float* g0  = (const float*)d_in[4];
    const float* be0 = (const float*)d_in[5];
    const float* W1  = (const float*)d_in[6];
    const float* b1  = (const float*)d_in[7];
    const float* g1  = (const float*)d_in[8];
    const float* be1 = (const float*)d_in[9];
    const float* W2  = (const float*)d_in[10];
    const float* b2  = (const float*)d_in[11];
    float* out = (float*)d_out;

    const int N = in_sizes[0] / 128;   // 170000
    const int E = in_sizes[1] / 2;     // 1200000
    const int nb = (N + 255) / 256;    // 665 (<= 1024 required by k_scan_sums)

    // ws layout (4B units): dinv | rs | csr_src | bsum | stats0 | stats1 | w2pad | bufA | bufB
    float* ws     = (float*)d_ws;
    size_t Npad   = ((size_t)N + 511) & ~(size_t)511;
    float* dinv   = ws;
    int*   rs     = (int*)(ws + Npad);           // N+1 slots (only N used + spare)
    int*   csr    = rs + Npad + 8;
    int*   bsum   = csr + ((E + 255) & ~255);
    float* stats0 = (float*)(bsum + 1024);
    float* stats1 = stats0 + 256;
    float* w2pad  = stats1 + 256;
    float* bufA   = w2pad + 16384;
    float* bufB   = bufA + (size_t)N * 128;

    hipMemsetAsync(rs, 0, (size_t)(N + 1) * sizeof(int), stream);
    hipMemsetAsync(stats0, 0, 512 * sizeof(float), stream);

    // ---- CSR build ----
    k_count    <<<(E + 255) / 256, 256, 0, stream>>>(ei, rs, E, N);
    k_dinv     <<<nb, 256, 0, stream>>>(rs, dinv, N);
    k_scan_part<<<nb, 256, 0, stream>>>(rs, bsum, N);
    k_scan_sums<<<1, 1024, 0, stream>>>(bsum, nb);
    k_scan_add <<<nb, 256, 0, stream>>>(rs, bsum, N);
    k_fill     <<<(E + 255) / 256, 256, 0, stream>>>(ei, rs, csr, E, N);
    k_padW2    <<<64, 256, 0, stream>>>(W2, w2pad);

    int gemm_grid = (N + 31) / 32;
    int a128_grid = (N + 7) / 8;
    int a40_grid  = (N + 15) / 16;

    // ---- layer 0 ----
    k_gemm128<<<gemm_grid, 256, 0, stream>>>(x, W0, bufA, N, nullptr, nullptr, nullptr);
    k_agg128 <<<a128_grid, 256, 0, stream>>>(bufA, rs, csr, dinv, b0, bufB, N);
    k_bnstats<<<1024, 128, 0, stream>>>(bufB, stats0, N);

    // ---- layer 1 (BN0+ReLU fused into GEMM load) ----
    k_gemm128<<<gemm_grid, 256, 0, stream>>>(bufB, W1, bufA, N, stats0, g0, be0);
    k_agg128 <<<a128_grid, 256, 0, stream>>>(bufA, rs, csr, dinv, b1, bufB, N);
    k_bnstats<<<1024, 128, 0, stream>>>(bufB, stats1, N);

    // ---- layer 2 (BN1+ReLU fused) -> 40 ch ----
    k_gemm128<<<gemm_grid, 256, 0, stream>>>(bufB, w2pad, bufA, N, stats1, g1, be1);
    k_agg40  <<<a40_grid, 256, 0, stream>>>(bufA, rs, csr, dinv, b2, out, N);
}

// Round 4
// 764.787 us; speedup vs baseline: 7.1542x; 1.4250x over previous
//
#include <hip/hip_runtime.h>

#define BN_EPS 1e-5f

using bf16x8 = __attribute__((ext_vector_type(8))) short;
using f32x4  = __attribute__((ext_vector_type(4))) float;

__device__ __forceinline__ unsigned int f2bf(float f) {   // RTNE fp32->bf16
    unsigned int u = __float_as_uint(f);
    u += 0x7fffu + ((u >> 16) & 1u);
    return u >> 16;
}
__device__ __forceinline__ float bflo(unsigned int u) { return __uint_as_float(u << 16); }
__device__ __forceinline__ float bfhi(unsigned int u) { return __uint_as_float(u & 0xffff0000u); }

// =========================== CSR build (per call) ===========================
__global__ __launch_bounds__(256) void k_count(const int* __restrict__ ei,
                                               int* __restrict__ cnt, int E, int N) {
    int e = blockIdx.x * 256 + threadIdx.x;
    if (e < E) {
        int d = ei[E + e];
        if ((unsigned)d < (unsigned)N) atomicAdd(&cnt[d], 1);
    }
}

__global__ __launch_bounds__(256) void k_dinv(const int* __restrict__ cnt,
                                              float* __restrict__ dinv, int N) {
    int i = blockIdx.x * 256 + threadIdx.x;
    if (i < N) dinv[i] = rsqrtf((float)(1 + cnt[i]));  // +1 self-loop
}

__global__ __launch_bounds__(256) void k_scan_part(int* __restrict__ rs,
                                                   int* __restrict__ bsum, int N) {
    __shared__ int s[256];
    int i = blockIdx.x * 256 + threadIdx.x;
    int v = (i < N) ? rs[i] : 0;
    s[threadIdx.x] = v;
    __syncthreads();
    for (int off = 1; off < 256; off <<= 1) {
        int t = (threadIdx.x >= off) ? s[threadIdx.x - off] : 0;
        __syncthreads();
        s[threadIdx.x] += t;
        __syncthreads();
    }
    if (i < N) rs[i] = s[threadIdx.x] - v;            // exclusive
    if (threadIdx.x == 255) bsum[blockIdx.x] = s[255];
}

__global__ __launch_bounds__(1024) void k_scan_sums(int* __restrict__ bsum, int nb) {
    __shared__ int s[1024];
    int v = (threadIdx.x < nb) ? bsum[threadIdx.x] : 0;
    s[threadIdx.x] = v;
    __syncthreads();
    for (int off = 1; off < 1024; off <<= 1) {
        int t = (threadIdx.x >= off) ? s[threadIdx.x - off] : 0;
        __syncthreads();
        s[threadIdx.x] += t;
        __syncthreads();
    }
    if (threadIdx.x < nb) bsum[threadIdx.x] = s[threadIdx.x] - v;  // exclusive
}

__global__ __launch_bounds__(256) void k_scan_add(int* __restrict__ rs,
                                                  const int* __restrict__ bsum, int N) {
    int i = blockIdx.x * 256 + threadIdx.x;
    if (i < N) rs[i] += bsum[blockIdx.x];
}

// post-increment fill: afterwards rs[d] == end offset of node d
__global__ __launch_bounds__(256) void k_fill(const int* __restrict__ ei,
                                              int* __restrict__ rs,
                                              int* __restrict__ csr_src, int E, int N) {
    int e = blockIdx.x * 256 + threadIdx.x;
    if (e >= E) return;
    int s = ei[e], d = ei[E + e];
    if ((unsigned)s >= (unsigned)N || (unsigned)d >= (unsigned)N) return;
    int pos = atomicAdd(&rs[d], 1);
    csr_src[pos] = s;
}

// ==================== weight prep: bf16 B-fragment order ====================
// Wf[((ct*4+kt)*64 + lane)*8 + j] = bf16(W[kt*32+(lane>>4)*8+j][ct*16+(lane&15)])
// (zero-padded when col >= C). 2048 threads, one 16B frag-slot each.
__global__ __launch_bounds__(256) void k_prepW(const float* __restrict__ W,
                                               unsigned short* __restrict__ Wf, int C) {
    int t = blockIdx.x * 256 + threadIdx.x;
    if (t >= 2048) return;
    int lane = t & 63, frag = t >> 6;
    int kt = frag & 3, ct = frag >> 2;
    int r = lane & 15, q = lane >> 4;
    int col = ct * 16 + r;
    int kbase = kt * 32 + q * 8;
    unsigned int v[8];
    #pragma unroll
    for (int j = 0; j < 8; ++j)
        v[j] = (col < C) ? f2bf(W[(size_t)(kbase + j) * C + col]) : 0u;
    uint4 o;
    o.x = v[0] | (v[1] << 16);
    o.y = v[2] | (v[3] << 16);
    o.z = v[4] | (v[5] << 16);
    o.w = v[6] | (v[7] << 16);
    ((uint4*)Wf)[t] = o;
}

// ============================== MFMA GEMM ===================================
__device__ __forceinline__ float bn_apply(float v, int c, const float* stats,
                                          const float* g, const float* be, float invN) {
    float mean = stats[c] * invN;
    float var  = fmaf(-mean, mean, stats[128 + c] * invN);
    float sc   = g[c] * rsqrtf(var + BN_EPS);
    float r    = fmaf(v - mean, sc, be[c]);
    return fmaxf(r, 0.0f);
}

// H_bf16[N,128] = bf16( bn_relu(X_f32) @ W ).  64 rows/block, 4 waves,
// wave w -> row-tile w (16 rows) x 8 col-tiles; K=128 in 4 MFMA steps.
__global__ __launch_bounds__(256) void k_gemm_mfma(
        const float* __restrict__ X, const unsigned short* __restrict__ Wf,
        unsigned short* __restrict__ H, int N,
        const float* __restrict__ stats, const float* __restrict__ g,
        const float* __restrict__ be) {
    __shared__ unsigned short aF[16 * 512];   // 16 A-frags  (16 KB), frag order
    __shared__ unsigned short bF[32 * 512];   // 32 B-frags  (32 KB), frag order
    const int tid = threadIdx.x;
    const int rowbase = blockIdx.x * 64;
    const float invN = 1.0f / (float)N;

    // stage B: straight 32 KB copy, lane-contiguous (conflict-free)
    {
        const uint4* src = (const uint4*)Wf;
        uint4* dst = (uint4*)bF;
        #pragma unroll
        for (int i = 0; i < 8; ++i) dst[tid + 256 * i] = src[tid + 256 * i];
    }
    // stage A: one frag-slot (8 contiguous k of one row) per task, BN fused
    #pragma unroll
    for (int it = 0; it < 4; ++it) {
        int f = tid + 256 * it;               // (rt*4+kt)*64 + lane
        int lane = f & 63, frag = f >> 6;
        int kt = frag & 3, rt = frag >> 2;
        int r = lane & 15, q = lane >> 4;
        int row = rowbase + rt * 16 + r;
        int kc = kt * 32 + q * 8;
        float vv[8];
        if (row < N) {
            const float4* xp = (const float4*)(X + (size_t)row * 128 + kc);
            float4 p0 = xp[0], p1 = xp[1];
            vv[0] = p0.x; vv[1] = p0.y; vv[2] = p0.z; vv[3] = p0.w;
            vv[4] = p1.x; vv[5] = p1.y; vv[6] = p1.z; vv[7] = p1.w;
            if (stats) {
                #pragma unroll
                for (int j = 0; j < 8; ++j)
                    vv[j] = bn_apply(vv[j], kc + j, stats, g, be, invN);
            }
        } else {
            #pragma unroll
            for (int j = 0; j < 8; ++j) vv[j] = 0.0f;
        }
        uint4 o;
        o.x = f2bf(vv[0]) | (f2bf(vv[1]) << 16);
        o.y = f2bf(vv[2]) | (f2bf(vv[3]) << 16);
        o.z = f2bf(vv[4]) | (f2bf(vv[5]) << 16);
        o.w = f2bf(vv[6]) | (f2bf(vv[7]) << 16);
        ((uint4*)aF)[f] = o;
    }
    __syncthreads();

    const int wave = tid >> 6, lane = tid & 63;
    f32x4 acc[8];
    #pragma unroll
    for (int ct = 0; ct < 8; ++ct) acc[ct] = (f32x4){0.f, 0.f, 0.f, 0.f};

    #pragma unroll
    for (int kt = 0; kt < 4; ++kt) {
        bf16x8 a = ((const bf16x8*)aF)[(wave * 4 + kt) * 64 + lane];
        #pragma unroll
        for (int ct = 0; ct < 8; ++ct) {
            bf16x8 b = ((const bf16x8*)bF)[(ct * 4 + kt) * 64 + lane];
            acc[ct] = __builtin_amdgcn_mfma_f32_16x16x32_bf16(a, b, acc[ct], 0, 0, 0);
        }
    }

    // C/D layout: col = lane&15, row = (lane>>4)*4 + reg
    const int q = lane >> 4, r = lane & 15;
    #pragma unroll
    for (int ct = 0; ct < 8; ++ct) {
        #pragma unroll
        for (int i = 0; i < 4; ++i) {
            int row = rowbase + wave * 16 + q * 4 + i;
            if (row < N)
                H[(size_t)row * 128 + ct * 16 + r] = (unsigned short)f2bf(acc[ct][i]);
        }
    }
}

// ========================= gather-based aggregate ===========================
// out[d] = b + H[d]*dinv[d]^2 + sum_{s in nbr(d)} H[s]*dinv[s]*dinv[d]
__global__ __launch_bounds__(256) void k_agg128(
        const unsigned short* __restrict__ H, const int* __restrict__ rs_end,
        const int* __restrict__ csr_src, const float* __restrict__ dinv,
        const float* __restrict__ b, float* __restrict__ out, int N) {
    int lane = threadIdx.x & 31;
    int node = blockIdx.x * 8 + (threadIdx.x >> 5);
    if (node >= N) return;
    float dd  = dinv[node];
    int   beg = (node == 0) ? 0 : rs_end[node - 1];
    int   end = rs_end[node];
    uint2 hp  = ((const uint2*)(H + (size_t)node * 128))[lane];
    float4 bb = ((const float4*)b)[lane];
    float  sl = dd * dd;
    float4 acc = make_float4(fmaf(bflo(hp.x), sl, bb.x), fmaf(bfhi(hp.x), sl, bb.y),
                             fmaf(bflo(hp.y), sl, bb.z), fmaf(bfhi(hp.y), sl, bb.w));
    int j = beg;
    for (; j + 2 <= end; j += 2) {
        int s0 = csr_src[j], s1 = csr_src[j + 1];
        float n0 = dinv[s0] * dd, n1 = dinv[s1] * dd;
        uint2 v0 = ((const uint2*)(H + (size_t)s0 * 128))[lane];
        uint2 v1 = ((const uint2*)(H + (size_t)s1 * 128))[lane];
        acc.x = fmaf(bflo(v0.x), n0, fmaf(bflo(v1.x), n1, acc.x));
        acc.y = fmaf(bfhi(v0.x), n0, fmaf(bfhi(v1.x), n1, acc.y));
        acc.z = fmaf(bflo(v0.y), n0, fmaf(bflo(v1.y), n1, acc.z));
        acc.w = fmaf(bfhi(v0.y), n0, fmaf(bfhi(v1.y), n1, acc.w));
    }
    if (j < end) {
        int s0 = csr_src[j];
        float n0 = dinv[s0] * dd;
        uint2 v0 = ((const uint2*)(H + (size_t)s0 * 128))[lane];
        acc.x = fmaf(bflo(v0.x), n0, acc.x);
        acc.y = fmaf(bfhi(v0.x), n0, acc.y);
        acc.z = fmaf(bflo(v0.y), n0, acc.z);
        acc.w = fmaf(bfhi(v0.y), n0, acc.w);
    }
    ((float4*)(out + (size_t)node * 128))[lane] = acc;
}

// 40-ch final: 16-lane groups, lanes 0..9 carry 4 channels (H stride 128)
__global__ __launch_bounds__(256) void k_agg40(
        const unsigned short* __restrict__ H, const int* __restrict__ rs_end,
        const int* __restrict__ csr_src, const float* __restrict__ dinv,
        const float* __restrict__ b, float* __restrict__ out, int N) {
    int lane = threadIdx.x & 15;
    int node = blockIdx.x * 16 + (threadIdx.x >> 4);
    if (node >= N || lane >= 10) return;
    float dd  = dinv[node];
    int   beg = (node == 0) ? 0 : rs_end[node - 1];
    int   end = rs_end[node];
    uint2 hp  = ((const uint2*)(H + (size_t)node * 128))[lane];
    float4 bb = ((const float4*)b)[lane];
    float  sl = dd * dd;
    float4 acc = make_float4(fmaf(bflo(hp.x), sl, bb.x), fmaf(bfhi(hp.x), sl, bb.y),
                             fmaf(bflo(hp.y), sl, bb.z), fmaf(bfhi(hp.y), sl, bb.w));
    for (int j = beg; j < end; ++j) {
        int s0 = csr_src[j];
        float n0 = dinv[s0] * dd;
        uint2 v0 = ((const uint2*)(H + (size_t)s0 * 128))[lane];
        acc.x = fmaf(bflo(v0.x), n0, acc.x);
        acc.y = fmaf(bfhi(v0.x), n0, acc.y);
        acc.z = fmaf(bflo(v0.y), n0, acc.z);
        acc.w = fmaf(bfhi(v0.y), n0, acc.w);
    }
    ((float4*)(out + (size_t)node * 40))[lane] = acc;
}

// =============================== BN stats ===================================
__global__ __launch_bounds__(128) void k_bnstats(
        const float* __restrict__ H, float* __restrict__ stats, int N) {
    int c = threadIdx.x;
    float s = 0.f, s2 = 0.f;
    for (int r = blockIdx.x; r < N; r += gridDim.x) {
        float v = H[(size_t)r * 128 + c];
        s += v;
        s2 = fmaf(v, v, s2);
    }
    unsafeAtomicAdd(&stats[c], s);
    unsafeAtomicAdd(&stats[128 + c], s2);
}

// ================================ launch ====================================
extern "C" void kernel_launch(void* const* d_in, const int* in_sizes, int n_in,
                              void* d_out, int out_size, void* d_ws, size_t ws_size,
                              hipStream_t stream) {
    const float* x   = (const float*)d_in[0];
    const int*   ei  = (const int*)d_in[1];      // int64 in ref -> int32 from harness
    const float* W0  = (const float*)d_in[2];
    const float* b0  = (const float*)d_in[3];
    const float* g0  = (const float*)d_in[4];
    const float* be0 = (const float*)d_in[5];
    const float* W1  = (const float*)d_in[6];
    const float* b1  = (const float*)d_in[7];
    const float* g1  = (const float*)d_in[8];
    const float* be1 = (const float*)d_in[9];
    const float* W2  = (const float*)d_in[10];
    const float* b2  = (const float*)d_in[11];
    float* out = (float*)d_out;

    const int N  = in_sizes[0] / 128;   // 170000
    const int E  = in_sizes[1] / 2;     // 1200000
    const int nb = (N + 255) / 256;     // 665 (<=1024)

    // ws layout (4B units)
    float* ws     = (float*)d_ws;
    size_t Npad   = ((size_t)N + 511) & ~(size_t)511;
    float* dinv   = ws;
    int*   rs     = (int*)(ws + Npad);
    int*   csr    = rs + Npad + 16;
    int*   bsum   = csr + ((E + 255) & ~255);
    float* stats0 = (float*)(bsum + 1024);
    float* stats1 = stats0 + 256;
    unsigned short* Wf0 = (unsigned short*)(stats1 + 256);   // 16384 ushort each
    unsigned short* Wf1 = Wf0 + 16384;
    unsigned short* Wf2 = Wf1 + 16384;
    unsigned short* Hb  = Wf2 + 16384;                       // N*128 bf16
    float* bufB   = (float*)(Hb + (size_t)Npad * 128);       // N*128 f32

    hipMemsetAsync(rs, 0, (size_t)(N + 1) * sizeof(int), stream);
    hipMemsetAsync(stats0, 0, 512 * sizeof(float), stream);

    // ---- CSR build + weight prep ----
    k_count    <<<(E + 255) / 256, 256, 0, stream>>>(ei, rs, E, N);
    k_dinv     <<<nb, 256, 0, stream>>>(rs, dinv, N);
    k_scan_part<<<nb, 256, 0, stream>>>(rs, bsum, N);
    k_scan_sums<<<1, 1024, 0, stream>>>(bsum, nb);
    k_scan_add <<<nb, 256, 0, stream>>>(rs, bsum, N);
    k_fill     <<<(E + 255) / 256, 256, 0, stream>>>(ei, rs, csr, E, N);
    k_prepW    <<<8, 256, 0, stream>>>(W0, Wf0, 128);
    k_prepW    <<<8, 256, 0, stream>>>(W1, Wf1, 128);
    k_prepW    <<<8, 256, 0, stream>>>(W2, Wf2, 40);

    int gemm_grid = (N + 63) / 64;
    int a128_grid = (N + 7) / 8;
    int a40_grid  = (N + 15) / 16;

    // ---- layer 0 ----
    k_gemm_mfma<<<gemm_grid, 256, 0, stream>>>(x, Wf0, Hb, N, nullptr, nullptr, nullptr);
    k_agg128   <<<a128_grid, 256, 0, stream>>>(Hb, rs, csr, dinv, b0, bufB, N);
    k_bnstats  <<<1024, 128, 0, stream>>>(bufB, stats0, N);

    // ---- layer 1 (BN0+ReLU fused into GEMM staging) ----
    k_gemm_mfma<<<gemm_grid, 256, 0, stream>>>(bufB, Wf1, Hb, N, stats0, g0, be0);
    k_agg128   <<<a128_grid, 256, 0, stream>>>(Hb, rs, csr, dinv, b1, bufB, N);
    k_bnstats  <<<1024, 128, 0, stream>>>(bufB, stats1, N);

    // ---- layer 2 (BN1+ReLU fused) -> 40 ch ----
    k_gemm_mfma<<<gemm_grid, 256, 0, stream>>>(bufB, Wf2, Hb, N, stats1, g1, be1);
    k_agg40    <<<a40_grid, 256, 0, stream>>>(Hb, rs, csr, dinv, b2, out, N);
}

// Round 5
// 677.441 us; speedup vs baseline: 8.0766x; 1.1289x over previous
//
#include <hip/hip_runtime.h>

#define BN_EPS 1e-5f

using bf16x8 = __attribute__((ext_vector_type(8))) short;
using f32x4  = __attribute__((ext_vector_type(4))) float;

__device__ __forceinline__ unsigned int f2bf(float f) {   // RTNE fp32->bf16
    unsigned int u = __float_as_uint(f);
    u += 0x7fffu + ((u >> 16) & 1u);
    return u >> 16;
}
__device__ __forceinline__ float bflo(unsigned int u) { return __uint_as_float(u << 16); }
__device__ __forceinline__ float bfhi(unsigned int u) { return __uint_as_float(u & 0xffff0000u); }

// ================= CSR build: two-phase counting sort by dst ================
// bucket b = dst >> 8 (256 nodes per bucket), NB = ceil(N/256) <= 768

// Phase A1: bucket histogram. 4096 edges/block.
__global__ __launch_bounds__(256) void k_bhist(const int* __restrict__ ei,
                                               int* __restrict__ bcnt, int E, int NB) {
    __shared__ int h[768];
    for (int i = threadIdx.x; i < 768; i += 256) h[i] = 0;
    __syncthreads();
    int base = blockIdx.x * 4096;
    #pragma unroll
    for (int it = 0; it < 16; ++it) {
        int e = base + it * 256 + threadIdx.x;
        if (e < E) atomicAdd(&h[ei[E + e] >> 8], 1);
    }
    __syncthreads();
    for (int i = threadIdx.x; i < NB; i += 256)
        if (h[i]) atomicAdd(&bcnt[i], h[i]);
}

// exclusive scan of bucket counts -> bbase[0..NB] (bbase[NB]=E), cursor copy
__global__ __launch_bounds__(1024) void k_bscan(const int* __restrict__ bcnt,
                                                int* __restrict__ bbase,
                                                int* __restrict__ bcur, int NB) {
    __shared__ int s[1024];
    int v = (threadIdx.x < NB) ? bcnt[threadIdx.x] : 0;
    s[threadIdx.x] = v;
    __syncthreads();
    for (int off = 1; off < 1024; off <<= 1) {
        int t = (threadIdx.x >= off) ? s[threadIdx.x - off] : 0;
        __syncthreads();
        s[threadIdx.x] += t;
        __syncthreads();
    }
    if (threadIdx.x < NB) {
        int ex = s[threadIdx.x] - v;
        bbase[threadIdx.x] = ex;
        bcur[threadIdx.x]  = ex;
    }
    if (threadIdx.x == 1023) bbase[NB] = s[1023];
}

// Phase A2: scatter (src,dst) into bucket-sorted ebuf via per-block chunk claims
__global__ __launch_bounds__(256) void k_bscatter(const int* __restrict__ ei,
                                                  int* __restrict__ bcur,
                                                  uint2* __restrict__ ebuf, int E, int NB) {
    __shared__ int h[768];
    __shared__ int wb[768];
    for (int i = threadIdx.x; i < 768; i += 256) h[i] = 0;
    __syncthreads();
    int base = blockIdx.x * 4096;
    int rk[16];
    #pragma unroll
    for (int it = 0; it < 16; ++it) {
        int e = base + it * 256 + threadIdx.x;
        rk[it] = (e < E) ? atomicAdd(&h[ei[E + e] >> 8], 1) : 0;
    }
    __syncthreads();
    for (int i = threadIdx.x; i < NB; i += 256) {
        int c = h[i];
        wb[i] = c ? atomicAdd(&bcur[i], c) : 0;
    }
    __syncthreads();
    #pragma unroll
    for (int it = 0; it < 16; ++it) {
        int e = base + it * 256 + threadIdx.x;
        if (e < E) {
            int s = ei[e], d = ei[E + e];
            ebuf[wb[d >> 8] + rk[it]] = make_uint2((unsigned)s, (unsigned)d);
        }
    }
}

// Phase B1: per-bucket node counts -> rs (coalesced), dinv fused
__global__ __launch_bounds__(256) void k_bcount(const uint2* __restrict__ ebuf,
                                                const int* __restrict__ bbase,
                                                int* __restrict__ rs,
                                                float* __restrict__ dinv, int N) {
    __shared__ int cnt[256];
    cnt[threadIdx.x] = 0;
    __syncthreads();
    int b = blockIdx.x;
    int beg = bbase[b], end = bbase[b + 1];
    for (int j = beg + threadIdx.x; j < end; j += 256)
        atomicAdd(&cnt[ebuf[j].y & 255], 1);
    __syncthreads();
    int node = b * 256 + threadIdx.x;
    if (node < N) {
        int c = cnt[threadIdx.x];
        rs[node]   = c;
        dinv[node] = rsqrtf((float)(1 + c));   // +1 self-loop
    }
}

// exclusive scan over rs[0..N-1] (3 kernels, in place)
__global__ __launch_bounds__(256) void k_scan_part(int* __restrict__ rs,
                                                   int* __restrict__ bsum, int N) {
    __shared__ int s[256];
    int i = blockIdx.x * 256 + threadIdx.x;
    int v = (i < N) ? rs[i] : 0;
    s[threadIdx.x] = v;
    __syncthreads();
    for (int off = 1; off < 256; off <<= 1) {
        int t = (threadIdx.x >= off) ? s[threadIdx.x - off] : 0;
        __syncthreads();
        s[threadIdx.x] += t;
        __syncthreads();
    }
    if (i < N) rs[i] = s[threadIdx.x] - v;
    if (threadIdx.x == 255) bsum[blockIdx.x] = s[255];
}

__global__ __launch_bounds__(1024) void k_scan_sums(int* __restrict__ bsum, int nb) {
    __shared__ int s[1024];
    int v = (threadIdx.x < nb) ? bsum[threadIdx.x] : 0;
    s[threadIdx.x] = v;
    __syncthreads();
    for (int off = 1; off < 1024; off <<= 1) {
        int t = (threadIdx.x >= off) ? s[threadIdx.x - off] : 0;
        __syncthreads();
        s[threadIdx.x] += t;
        __syncthreads();
    }
    if (threadIdx.x < nb) bsum[threadIdx.x] = s[threadIdx.x] - v;
}

__global__ __launch_bounds__(256) void k_scan_add(int* __restrict__ rs,
                                                  const int* __restrict__ bsum, int N) {
    int i = blockIdx.x * 256 + threadIdx.x;
    if (i < N) rs[i] += bsum[blockIdx.x];
}

// Phase B2: place edges into csr via LDS node cursors (writes stay in-bucket)
__global__ __launch_bounds__(256) void k_bplace(const uint2* __restrict__ ebuf,
                                                const int* __restrict__ bbase,
                                                const int* __restrict__ rs,
                                                int* __restrict__ csr, int N) {
    __shared__ int cur[256];
    int b = blockIdx.x;
    int node = b * 256 + threadIdx.x;
    cur[threadIdx.x] = (node < N) ? rs[node] : 0;
    __syncthreads();
    int beg = bbase[b], end = bbase[b + 1];
    for (int j = beg + threadIdx.x; j < end; j += 256) {
        uint2 e = ebuf[j];
        int pos = atomicAdd(&cur[e.y & 255], 1);
        csr[pos] = (int)e.x;
    }
}

// ==================== weight prep: bf16 B-fragment order ====================
__global__ __launch_bounds__(256) void k_prepW(const float* __restrict__ W,
                                               unsigned short* __restrict__ Wf, int C) {
    int t = blockIdx.x * 256 + threadIdx.x;
    if (t >= 2048) return;
    int lane = t & 63, frag = t >> 6;
    int kt = frag & 3, ct = frag >> 2;
    int r = lane & 15, q = lane >> 4;
    int col = ct * 16 + r;
    int kbase = kt * 32 + q * 8;
    unsigned int v[8];
    #pragma unroll
    for (int j = 0; j < 8; ++j)
        v[j] = (col < C) ? f2bf(W[(size_t)(kbase + j) * C + col]) : 0u;
    uint4 o;
    o.x = v[0] | (v[1] << 16);
    o.y = v[2] | (v[3] << 16);
    o.z = v[4] | (v[5] << 16);
    o.w = v[6] | (v[7] << 16);
    ((uint4*)Wf)[t] = o;
}

// ============================== MFMA GEMM ===================================
__device__ __forceinline__ float bn_apply(float v, int c, const float* stats,
                                          const float* g, const float* be, float invN) {
    float mean = stats[c] * invN;
    float var  = fmaf(-mean, mean, stats[128 + c] * invN);
    float sc   = g[c] * rsqrtf(var + BN_EPS);
    float r    = fmaf(v - mean, sc, be[c]);
    return fmaxf(r, 0.0f);
}

// H_bf16[N,128] = bf16( bn_relu(X) @ W ).  X is f32 (xf32=1) or bf16 (xf32=0).
__global__ __launch_bounds__(256) void k_gemm_mfma(
        const void* __restrict__ X, int xf32, const unsigned short* __restrict__ Wf,
        unsigned short* __restrict__ H, int N,
        const float* __restrict__ stats, const float* __restrict__ g,
        const float* __restrict__ be) {
    __shared__ unsigned short aF[16 * 512];   // 16 KB, A frags
    __shared__ unsigned short bF[32 * 512];   // 32 KB, B frags
    const int tid = threadIdx.x;
    const int rowbase = blockIdx.x * 64;
    const float invN = 1.0f / (float)N;

    {   // stage B: straight copy, lane-contiguous
        const uint4* src = (const uint4*)Wf;
        uint4* dst = (uint4*)bF;
        #pragma unroll
        for (int i = 0; i < 8; ++i) dst[tid + 256 * i] = src[tid + 256 * i];
    }
    // stage A: one frag-slot (8 contiguous k of one row), BN+ReLU fused
    #pragma unroll
    for (int it = 0; it < 4; ++it) {
        int f = tid + 256 * it;
        int lane = f & 63, frag = f >> 6;
        int kt = frag & 3, rt = frag >> 2;
        int r = lane & 15, q = lane >> 4;
        int row = rowbase + rt * 16 + r;
        int kc = kt * 32 + q * 8;
        float vv[8];
        if (row < N) {
            if (xf32) {
                const float4* xp = (const float4*)((const float*)X + (size_t)row * 128 + kc);
                float4 p0 = xp[0], p1 = xp[1];
                vv[0] = p0.x; vv[1] = p0.y; vv[2] = p0.z; vv[3] = p0.w;
                vv[4] = p1.x; vv[5] = p1.y; vv[6] = p1.z; vv[7] = p1.w;
            } else {
                uint4 p = *((const uint4*)((const unsigned short*)X + (size_t)row * 128 + kc));
                vv[0] = bflo(p.x); vv[1] = bfhi(p.x);
                vv[2] = bflo(p.y); vv[3] = bfhi(p.y);
                vv[4] = bflo(p.z); vv[5] = bfhi(p.z);
                vv[6] = bflo(p.w); vv[7] = bfhi(p.w);
            }
            if (stats) {
                #pragma unroll
                for (int j = 0; j < 8; ++j)
                    vv[j] = bn_apply(vv[j], kc + j, stats, g, be, invN);
            }
        } else {
            #pragma unroll
            for (int j = 0; j < 8; ++j) vv[j] = 0.0f;
        }
        uint4 o;
        o.x = f2bf(vv[0]) | (f2bf(vv[1]) << 16);
        o.y = f2bf(vv[2]) | (f2bf(vv[3]) << 16);
        o.z = f2bf(vv[4]) | (f2bf(vv[5]) << 16);
        o.w = f2bf(vv[6]) | (f2bf(vv[7]) << 16);
        ((uint4*)aF)[f] = o;
    }
    __syncthreads();

    const int wave = tid >> 6, lane = tid & 63;
    f32x4 acc[8];
    #pragma unroll
    for (int ct = 0; ct < 8; ++ct) acc[ct] = (f32x4){0.f, 0.f, 0.f, 0.f};

    #pragma unroll
    for (int kt = 0; kt < 4; ++kt) {
        bf16x8 a = ((const bf16x8*)aF)[(wave * 4 + kt) * 64 + lane];
        #pragma unroll
        for (int ct = 0; ct < 8; ++ct) {
            bf16x8 b = ((const bf16x8*)bF)[(ct * 4 + kt) * 64 + lane];
            acc[ct] = __builtin_amdgcn_mfma_f32_16x16x32_bf16(a, b, acc[ct], 0, 0, 0);
        }
    }

    const int q = lane >> 4, r = lane & 15;   // C/D: col=lane&15, row=q*4+reg
    #pragma unroll
    for (int ct = 0; ct < 8; ++ct) {
        #pragma unroll
        for (int i = 0; i < 4; ++i) {
            int row = rowbase + wave * 16 + q * 4 + i;
            if (row < N)
                H[(size_t)row * 128 + ct * 16 + r] = (unsigned short)f2bf(acc[ct][i]);
        }
    }
}

// ========================= gather-based aggregate ===========================
// out_bf16[d] = b + H[d]*dinv[d]^2 + sum_s H[s]*dinv[s]*dinv[d]
// rs[d] = exclusive start; end = rs[d+1] (E for d==N-1)
__global__ __launch_bounds__(256) void k_agg128(
        const unsigned short* __restrict__ H, const int* __restrict__ rs,
        const int* __restrict__ csr_src, const float* __restrict__ dinv,
        const float* __restrict__ b, unsigned short* __restrict__ outb, int N, int E) {
    int lane = threadIdx.x & 31;
    int node = blockIdx.x * 8 + (threadIdx.x >> 5);
    if (node >= N) return;
    float dd  = dinv[node];
    int   beg = rs[node];
    int   end = (node == N - 1) ? E : rs[node + 1];
    uint2 hp  = ((const uint2*)(H + (size_t)node * 128))[lane];
    float4 bb = ((const float4*)b)[lane];
    float  sl = dd * dd;
    float4 acc = make_float4(fmaf(bflo(hp.x), sl, bb.x), fmaf(bfhi(hp.x), sl, bb.y),
                             fmaf(bflo(hp.y), sl, bb.z), fmaf(bfhi(hp.y), sl, bb.w));
    int j = beg;
    for (; j + 2 <= end; j += 2) {
        int s0 = csr_src[j], s1 = csr_src[j + 1];
        float n0 = dinv[s0] * dd, n1 = dinv[s1] * dd;
        uint2 v0 = ((const uint2*)(H + (size_t)s0 * 128))[lane];
        uint2 v1 = ((const uint2*)(H + (size_t)s1 * 128))[lane];
        acc.x = fmaf(bflo(v0.x), n0, fmaf(bflo(v1.x), n1, acc.x));
        acc.y = fmaf(bfhi(v0.x), n0, fmaf(bfhi(v1.x), n1, acc.y));
        acc.z = fmaf(bflo(v0.y), n0, fmaf(bflo(v1.y), n1, acc.z));
        acc.w = fmaf(bfhi(v0.y), n0, fmaf(bfhi(v1.y), n1, acc.w));
    }
    if (j < end) {
        int s0 = csr_src[j];
        float n0 = dinv[s0] * dd;
        uint2 v0 = ((const uint2*)(H + (size_t)s0 * 128))[lane];
        acc.x = fmaf(bflo(v0.x), n0, acc.x);
        acc.y = fmaf(bfhi(v0.x), n0, acc.y);
        acc.z = fmaf(bflo(v0.y), n0, acc.z);
        acc.w = fmaf(bfhi(v0.y), n0, acc.w);
    }
    uint2 o;
    o.x = f2bf(acc.x) | (f2bf(acc.y) << 16);
    o.y = f2bf(acc.z) | (f2bf(acc.w) << 16);
    ((uint2*)(outb + (size_t)node * 128))[lane] = o;
}

// 40-ch final: f32 output
__global__ __launch_bounds__(256) void k_agg40(
        const unsigned short* __restrict__ H, const int* __restrict__ rs,
        const int* __restrict__ csr_src, const float* __restrict__ dinv,
        const float* __restrict__ b, float* __restrict__ out, int N, int E) {
    int lane = threadIdx.x & 15;
    int node = blockIdx.x * 16 + (threadIdx.x >> 4);
    if (node >= N || lane >= 10) return;
    float dd  = dinv[node];
    int   beg = rs[node];
    int   end = (node == N - 1) ? E : rs[node + 1];
    uint2 hp  = ((const uint2*)(H + (size_t)node * 128))[lane];
    float4 bb = ((const float4*)b)[lane];
    float  sl = dd * dd;
    float4 acc = make_float4(fmaf(bflo(hp.x), sl, bb.x), fmaf(bfhi(hp.x), sl, bb.y),
                             fmaf(bflo(hp.y), sl, bb.z), fmaf(bfhi(hp.y), sl, bb.w));
    for (int j = beg; j < end; ++j) {
        int s0 = csr_src[j];
        float n0 = dinv[s0] * dd;
        uint2 v0 = ((const uint2*)(H + (size_t)s0 * 128))[lane];
        acc.x = fmaf(bflo(v0.x), n0, acc.x);
        acc.y = fmaf(bfhi(v0.x), n0, acc.y);
        acc.z = fmaf(bflo(v0.y), n0, acc.z);
        acc.w = fmaf(bfhi(v0.y), n0, acc.w);
    }
    ((float4*)(out + (size_t)node * 40))[lane] = acc;
}

// =============================== BN stats ===================================
__global__ __launch_bounds__(128) void k_bnstats(
        const unsigned short* __restrict__ Hb, float* __restrict__ stats, int N) {
    int c = threadIdx.x;
    float s = 0.f, s2 = 0.f;
    for (int r = blockIdx.x; r < N; r += gridDim.x) {
        float v = bflo((unsigned)Hb[(size_t)r * 128 + c]);
        s += v;
        s2 = fmaf(v, v, s2);
    }
    unsafeAtomicAdd(&stats[c], s);
    unsafeAtomicAdd(&stats[128 + c], s2);
}

// ================================ launch ====================================
extern "C" void kernel_launch(void* const* d_in, const int* in_sizes, int n_in,
                              void* d_out, int out_size, void* d_ws, size_t ws_size,
                              hipStream_t stream) {
    const float* x   = (const float*)d_in[0];
    const int*   ei  = (const int*)d_in[1];      // int64 in ref -> int32 from harness
    const float* W0  = (const float*)d_in[2];
    const float* b0  = (const float*)d_in[3];
    const float* g0  = (const float*)d_in[4];
    const float* be0 = (const float*)d_in[5];
    const float* W1  = (const float*)d_in[6];
    const float* b1  = (const float*)d_in[7];
    const float* g1  = (const float*)d_in[8];
    const float* be1 = (const float*)d_in[9];
    const float* W2  = (const float*)d_in[10];
    const float* b2  = (const float*)d_in[11];
    float* out = (float*)d_out;

    const int N  = in_sizes[0] / 128;   // 170000
    const int E  = in_sizes[1] / 2;     // 1200000
    const int NB = (N + 255) >> 8;      // 665 buckets (<=768, <=1024)
    const int nb = (N + 255) / 256;     // scan blocks over nodes
    const int EB = (E + 4095) / 4096;   // 293 edge-chunk blocks

    // ws layout (4B units)
    float* ws     = (float*)d_ws;
    size_t Npad   = ((size_t)N + 511) & ~(size_t)511;
    size_t Epad   = ((size_t)E + 255) & ~(size_t)255;
    float* dinv   = ws;
    int*   rs     = (int*)(ws + Npad);                  // Npad+16
    int*   csr    = rs + Npad + 16;                     // Epad
    uint2* ebuf   = (uint2*)(csr + Epad);               // Epad uint2
    int*   bcnt   = (int*)(ebuf + Epad);                // 1024
    int*   bbase  = bcnt + 1024;                        // 1024 (NB+1 used)
    int*   bcur   = bbase + 1024;                       // 1024
    int*   bsum   = bcur + 1024;                        // 1024
    float* stats0 = (float*)(bsum + 1024);              // 256
    float* stats1 = stats0 + 256;                       // 256
    unsigned short* Wf0 = (unsigned short*)(stats1 + 256);  // 16384 ushort each
    unsigned short* Wf1 = Wf0 + 16384;
    unsigned short* Wf2 = Wf1 + 16384;
    unsigned short* Hb  = Wf2 + 16384;                  // Npad*128 bf16
    unsigned short* Bb  = Hb + Npad * 128;              // Npad*128 bf16

    hipMemsetAsync(bcnt, 0, 1024 * sizeof(int), stream);
    hipMemsetAsync(stats0, 0, 512 * sizeof(float), stream);

    // ---- CSR build (counting sort) + weight prep ----
    k_bhist    <<<EB, 256, 0, stream>>>(ei, bcnt, E, NB);
    k_bscan    <<<1, 1024, 0, stream>>>(bcnt, bbase, bcur, NB);
    k_bscatter <<<EB, 256, 0, stream>>>(ei, bcur, ebuf, E, NB);
    k_bcount   <<<NB, 256, 0, stream>>>(ebuf, bbase, rs, dinv, N);
    k_scan_part<<<nb, 256, 0, stream>>>(rs, bsum, N);
    k_scan_sums<<<1, 1024, 0, stream>>>(bsum, nb);
    k_scan_add <<<nb, 256, 0, stream>>>(rs, bsum, N);
    k_bplace   <<<NB, 256, 0, stream>>>(ebuf, bbase, rs, csr, N);
    k_prepW    <<<8, 256, 0, stream>>>(W0, Wf0, 128);
    k_prepW    <<<8, 256, 0, stream>>>(W1, Wf1, 128);
    k_prepW    <<<8, 256, 0, stream>>>(W2, Wf2, 40);

    int gemm_grid = (N + 63) / 64;
    int a128_grid = (N + 7) / 8;
    int a40_grid  = (N + 15) / 16;

    // ---- layer 0 ----
    k_gemm_mfma<<<gemm_grid, 256, 0, stream>>>(x, 1, Wf0, Hb, N, nullptr, nullptr, nullptr);
    k_agg128   <<<a128_grid, 256, 0, stream>>>(Hb, rs, csr, dinv, b0, Bb, N, E);
    k_bnstats  <<<1024, 128, 0, stream>>>(Bb, stats0, N);

    // ---- layer 1 (BN0+ReLU fused into GEMM staging) ----
    k_gemm_mfma<<<gemm_grid, 256, 0, stream>>>(Bb, 0, Wf1, Hb, N, stats0, g0, be0);
    k_agg128   <<<a128_grid, 256, 0, stream>>>(Hb, rs, csr, dinv, b1, Bb, N, E);
    k_bnstats  <<<1024, 128, 0, stream>>>(Bb, stats1, N);

    // ---- layer 2 (BN1+ReLU fused) -> 40 ch ----
    k_gemm_mfma<<<gemm_grid, 256, 0, stream>>>(Bb, 0, Wf2, Hb, N, stats1, g1, be1);
    k_agg40    <<<a40_grid, 256, 0, stream>>>(Hb, rs, csr, dinv, b2, out, N, E);
}